// Round 1
// baseline (448.459 us; speedup 1.0000x reference)
//
#include <hip/hip_runtime.h>
#include <stdint.h>

#define IN_F 768
#define HID 256
#define OUTF 128

typedef short bf16x8 __attribute__((ext_vector_type(8)));
typedef float f32x4 __attribute__((ext_vector_type(4)));

__device__ inline short f2bf(float f) {
  union { float f; uint32_t u; } x; x.f = f;
  uint32_t r = (x.u + 0x7fffu + ((x.u >> 16) & 1u)) >> 16;  // RNE, finite inputs
  return (short)(uint16_t)r;
}
__device__ inline float bf2f(uint32_t bits) {
  union { uint32_t u; float f; } x; x.u = bits << 16; return x.f;
}

// ---------------- prep: zero counters + transpose/convert both weights ----
// one launch covers: W1 transpose (IN_F*HID), W2 transpose (HID*OUTF),
// zero cnt[n+1] (last slot doubles as the global CSR allocator counter).
__global__ void k_prep(const float* __restrict__ W1, short* __restrict__ W1t,
                       const float* __restrict__ W2, short* __restrict__ W2t,
                       int* __restrict__ cnt, int nz) {
  int idx = blockIdx.x * blockDim.x + threadIdx.x;
  const int n1 = IN_F * HID;
  const int n2 = HID * OUTF;
  if (idx < n1) {
    int nn = idx / IN_F, kk = idx - nn * IN_F;
    W1t[idx] = f2bf(W1[kk * HID + nn]);
  } else if (idx < n1 + n2) {
    int j = idx - n1;
    int nn = j / HID, kk = j - nn * HID;
    W2t[j] = f2bf(W2[kk * OUTF + nn]);
  } else {
    int z = idx - n1 - n2;
    if (z < nz) cnt[z] = 0;
  }
}

__global__ void k_hist(const int* __restrict__ dst, int* __restrict__ cnt, int e) {
  int i = blockIdx.x * blockDim.x + threadIdx.x;
  if (i < e) atomicAdd(&cnt[dst[i]], 1);
}

// scan-free CSR row allocation: wave-local shuffle scan + 1 atomic per wave.
// Row ranges land in arbitrary order in ssrc — correctness only needs each
// node to own a private contiguous range, not index-ordered offsets.
__global__ void k_alloc(const int* __restrict__ cnt, int* __restrict__ rowp,
                        int* __restrict__ cursor, float* __restrict__ dinv,
                        int* __restrict__ gtot, int n) {
  int i = blockIdx.x * blockDim.x + threadIdx.x;
  int lane = threadIdx.x & 63;
  int v = (i < n) ? cnt[i] : 0;
  int incl = v;
#pragma unroll
  for (int off = 1; off < 64; off <<= 1) {
    int t = __shfl_up(incl, off);
    if (lane >= off) incl += t;
  }
  int wsum = __shfl(incl, 63);
  int base = 0;
  if (lane == 63) base = atomicAdd(gtot, wsum);
  base = __shfl(base, 63);
  if (i < n) {
    int start = base + incl - v;
    rowp[i] = start;
    cursor[i] = start;
    dinv[i] = rsqrtf((float)(v + 1));  // +1 self-loop
  }
}

__global__ void k_fill(const int* __restrict__ src, const int* __restrict__ dst,
                       int* __restrict__ cursor, int* __restrict__ ssrc, int e) {
  int i = blockIdx.x * blockDim.x + threadIdx.x;
  if (i < e) {
    int d = dst[i];
    int pos = atomicAdd(&cursor[d], 1);
    ssrc[pos] = src[i];
  }
}

// ---------------- GEMM1: C[M,256](bf16) = A[M,K](f32) @ Bt[256,K]^T -------
__global__ __launch_bounds__(256, 2) void k_gemm1(const float* __restrict__ A,
                                                  const short* __restrict__ Bt,
                                                  short* __restrict__ C,
                                                  int M, int K) {
  __shared__ __align__(16) short As[128 * 32];
  __shared__ __align__(16) short Bs[256 * 32];
  const int tid = threadIdx.x;
  const int tile_m = blockIdx.x * 128;
  const int wave = tid >> 6;
  const int lane = tid & 63;
  const int wm = (wave & 1) * 64;
  const int wn = (wave >> 1) * 128;
  const int lrow = lane & 15;
  const int quad = lane >> 4;

  const int rA0 = tid >> 2;
  const int colA = (tid & 3) * 8;
  const int rA1 = rA0 + 64;
  int gr0 = tile_m + rA0; if (gr0 >= M) gr0 = M - 1;
  int gr1 = tile_m + rA1; if (gr1 >= M) gr1 = M - 1;
  const float* pA0 = A + (size_t)gr0 * K + colA;
  const float* pA1 = A + (size_t)gr1 * K + colA;
  const short* pB = Bt + (size_t)rA0 * K + colA;

  float4 a0[2], a1[2];
  bf16x8 bgl[4];
  auto ldglb = [&](int k0) {
    a0[0] = *(const float4*)(pA0 + k0);
    a0[1] = *(const float4*)(pA0 + k0 + 4);
    a1[0] = *(const float4*)(pA1 + k0);
    a1[1] = *(const float4*)(pA1 + k0 + 4);
#pragma unroll
    for (int q = 0; q < 4; q++)
      bgl[q] = *(const bf16x8*)(pB + (size_t)(q * 64) * K + k0);
  };

  f32x4 zero = {0.f, 0.f, 0.f, 0.f};
  f32x4 acc[4][8];
#pragma unroll
  for (int i = 0; i < 4; i++)
#pragma unroll
    for (int j = 0; j < 8; j++) acc[i][j] = zero;

  ldglb(0);
  for (int k0 = 0; k0 < K; k0 += 32) {
    bf16x8 pk0, pk1;
    pk0[0] = f2bf(a0[0].x); pk0[1] = f2bf(a0[0].y); pk0[2] = f2bf(a0[0].z); pk0[3] = f2bf(a0[0].w);
    pk0[4] = f2bf(a0[1].x); pk0[5] = f2bf(a0[1].y); pk0[6] = f2bf(a0[1].z); pk0[7] = f2bf(a0[1].w);
    pk1[0] = f2bf(a1[0].x); pk1[1] = f2bf(a1[0].y); pk1[2] = f2bf(a1[0].z); pk1[3] = f2bf(a1[0].w);
    pk1[4] = f2bf(a1[1].x); pk1[5] = f2bf(a1[1].y); pk1[6] = f2bf(a1[1].z); pk1[7] = f2bf(a1[1].w);
    *(bf16x8*)&As[tid * 8] = pk0;
    *(bf16x8*)&As[(tid + 256) * 8] = pk1;
#pragma unroll
    for (int q = 0; q < 4; q++) *(bf16x8*)&Bs[(tid + q * 256) * 8] = bgl[q];
    __syncthreads();

    if (k0 + 32 < K) ldglb(k0 + 32);

    bf16x8 af[4], bfr[8];
#pragma unroll
    for (int i = 0; i < 4; i++)
      af[i] = *(const bf16x8*)&As[(wm + i * 16 + lrow) * 32 + quad * 8];
#pragma unroll
    for (int j = 0; j < 8; j++)
      bfr[j] = *(const bf16x8*)&Bs[(wn + j * 16 + lrow) * 32 + quad * 8];
#pragma unroll
    for (int i = 0; i < 4; i++)
#pragma unroll
      for (int j = 0; j < 8; j++)
        acc[i][j] = __builtin_amdgcn_mfma_f32_16x16x32_bf16(af[i], bfr[j],
                                                            acc[i][j], 0, 0, 0);
    __syncthreads();
  }

#pragma unroll
  for (int i = 0; i < 4; i++) {
#pragma unroll
    for (int r = 0; r < 4; r++) {
      int grow = tile_m + wm + i * 16 + quad * 4 + r;
      if (grow < M) {
#pragma unroll
        for (int j = 0; j < 8; j++) {
          int gcol = wn + j * 16 + lrow;
          C[(size_t)grow * HID + gcol] = f2bf(acc[i][j][r]);
        }
      }
    }
  }
}

// ---------------- async MFMA GEMM (m97 structure), bf16 A ----------------
__device__ inline void glds16(const short* g, short* l) {
  __builtin_amdgcn_global_load_lds((const __attribute__((address_space(1))) void*)g,
                                   (__attribute__((address_space(3))) void*)l, 16, 0, 0);
}

__global__ __launch_bounds__(256) void k_gemm_a(const short* __restrict__ A,
                                                const short* __restrict__ Bt,
                                                short* __restrict__ C,
                                                int M, int N, int K) {
  __shared__ __align__(16) short As[128 * 32];
  __shared__ __align__(16) short Bs[128 * 32];
  const int tid = threadIdx.x;
  const int tile_m = blockIdx.x * 128;
  const int tile_n = blockIdx.y * 128;
  const int wave = tid >> 6;
  const int lane = tid & 63;
  const int wm = (wave & 1) * 64;
  const int wn = (wave >> 1) * 64;
  const int lrow = lane & 15;
  const int quad = lane >> 4;

  const int c = tid, c2 = tid + 256;
  const int rowA = c >> 2, colA = (c & 3) * 8;
  const int rowA2 = c2 >> 2, colA2 = (c2 & 3) * 8;
  int grA = tile_m + rowA;  if (grA >= M) grA = M - 1;
  int grA2 = tile_m + rowA2; if (grA2 >= M) grA2 = M - 1;
  const short* pA = A + (size_t)grA * K + colA;
  const short* pA2 = A + (size_t)grA2 * K + colA2;
  const short* pB = Bt + (size_t)(tile_n + rowA) * K + colA;
  const short* pB2 = Bt + (size_t)(tile_n + rowA2) * K + colA2;

  f32x4 zero = {0.f, 0.f, 0.f, 0.f};
  f32x4 acc[4][4];
#pragma unroll
  for (int i = 0; i < 4; i++)
#pragma unroll
    for (int j = 0; j < 4; j++) acc[i][j] = zero;

  for (int k0 = 0; k0 < K; k0 += 32) {
    glds16(pA + k0, &As[c * 8]);
    glds16(pA2 + k0, &As[c2 * 8]);
    glds16(pB + k0, &Bs[c * 8]);
    glds16(pB2 + k0, &Bs[c2 * 8]);
    __builtin_amdgcn_s_waitcnt(0xcf70);  // vmcnt(0)
    __syncthreads();

    bf16x8 af[4], bfr[4];
#pragma unroll
    for (int i = 0; i < 4; i++)
      af[i] = *(const bf16x8*)&As[(wm + i * 16 + lrow) * 32 + quad * 8];
#pragma unroll
    for (int j = 0; j < 4; j++)
      bfr[j] = *(const bf16x8*)&Bs[(wn + j * 16 + lrow) * 32 + quad * 8];
#pragma unroll
    for (int i = 0; i < 4; i++)
#pragma unroll
      for (int j = 0; j < 4; j++)
        acc[i][j] = __builtin_amdgcn_mfma_f32_16x16x32_bf16(af[i], bfr[j],
                                                            acc[i][j], 0, 0, 0);
    __syncthreads();
  }

#pragma unroll
  for (int i = 0; i < 4; i++) {
#pragma unroll
    for (int r = 0; r < 4; r++) {
      int grow = tile_m + wm + i * 16 + quad * 4 + r;
      if (grow < M) {
#pragma unroll
        for (int j = 0; j < 4; j++) {
          int gcol = tile_n + wn + j * 16 + lrow;
          C[(size_t)grow * N + gcol] = f2bf(acc[i][j][r]);
        }
      }
    }
  }
}

// ---------------- CSR aggregation: wave/node, batch-preload edge metadata -
// Per 64-edge batch: ONE coalesced ssrc load + ONE dinv gather, then
// v_readlane broadcast per edge (uniform index). Removes the per-edge
// v_load -> readfirstlane -> s_load dependency chain; only the H-row
// gather remains per edge, 4 independent in flight.
template <int F, bool RELU, typename OT>
__global__ __launch_bounds__(256) void k_agg3(const short* __restrict__ H,
                                              const int* __restrict__ rowp,
                                              const int* __restrict__ cnt,
                                              const int* __restrict__ ssrc,
                                              const float* __restrict__ dinv,
                                              const float* __restrict__ bias,
                                              OT* __restrict__ out, int n) {
  constexpr int EPL = F / 64;  // 4 (F=256) or 2 (F=128)
  const int lane = threadIdx.x & 63;
  const int i = blockIdx.x * 4 + (threadIdx.x >> 6);
  if (i >= n) return;
  const int fo = lane * EPL;
  const float di = dinv[i];
  float acc[EPL];
  {
    const short* r = H + (size_t)i * F + fo;
    if constexpr (EPL == 4) {
      uint2 u = *(const uint2*)r;
      acc[0] = di * bf2f(u.x & 0xffffu); acc[1] = di * bf2f(u.x >> 16);
      acc[2] = di * bf2f(u.y & 0xffffu); acc[3] = di * bf2f(u.y >> 16);
    } else {
      uint32_t u = *(const uint32_t*)r;
      acc[0] = di * bf2f(u & 0xffffu); acc[1] = di * bf2f(u >> 16);
    }
  }

  const int p0 = rowp[i];
  const int deg = cnt[i];

  auto proc = [&](int sl, uint32_t dslu, int ee) {
    int sv = __builtin_amdgcn_readlane(sl, ee);
    float dsv = __uint_as_float((uint32_t)__builtin_amdgcn_readlane((int)dslu, ee));
    const short* r = H + (size_t)sv * F + fo;
    if constexpr (EPL == 4) {
      uint2 u = *(const uint2*)r;
      acc[0] += dsv * bf2f(u.x & 0xffffu); acc[1] += dsv * bf2f(u.x >> 16);
      acc[2] += dsv * bf2f(u.y & 0xffffu); acc[3] += dsv * bf2f(u.y >> 16);
    } else {
      uint32_t u = *(const uint32_t*)r;
      acc[0] += dsv * bf2f(u & 0xffffu); acc[1] += dsv * bf2f(u >> 16);
    }
  };

  for (int pb = 0; pb < deg; pb += 64) {
    const int rem = deg - pb;
    const int m = rem < 64 ? rem : 64;
    int sl = 0;
    uint32_t dslu = 0;
    if (lane < m) {
      sl = ssrc[p0 + pb + lane];
      dslu = __float_as_uint(dinv[sl]);
    }
    int e2 = 0;
    for (; e2 + 4 <= m; e2 += 4) {
      proc(sl, dslu, e2);
      proc(sl, dslu, e2 + 1);
      proc(sl, dslu, e2 + 2);
      proc(sl, dslu, e2 + 3);
    }
    for (; e2 < m; ++e2) proc(sl, dslu, e2);
  }

  float o[EPL];
#pragma unroll
  for (int e3 = 0; e3 < EPL; ++e3) {
    o[e3] = di * acc[e3] + bias[fo + e3];
    if (RELU) o[e3] = fmaxf(o[e3], 0.f);
  }
  if constexpr (sizeof(OT) == 2) {
    if constexpr (EPL == 4) {
      uint2 pk;
      pk.x = (uint32_t)(uint16_t)f2bf(o[0]) | ((uint32_t)(uint16_t)f2bf(o[1]) << 16);
      pk.y = (uint32_t)(uint16_t)f2bf(o[2]) | ((uint32_t)(uint16_t)f2bf(o[3]) << 16);
      *(uint2*)((short*)out + (size_t)i * F + fo) = pk;
    } else {
      uint32_t pk = (uint32_t)(uint16_t)f2bf(o[0]) | ((uint32_t)(uint16_t)f2bf(o[1]) << 16);
      *(uint32_t*)((short*)out + (size_t)i * F + fo) = pk;
    }
  } else {
    if constexpr (EPL == 4) {
      *(float4*)((float*)out + (size_t)i * F + fo) = make_float4(o[0], o[1], o[2], o[3]);
    } else {
      *(float2*)((float*)out + (size_t)i * F + fo) = make_float2(o[0], o[1]);
    }
  }
}

// ---------------- launch ----------------
extern "C" void kernel_launch(void* const* d_in, const int* in_sizes, int n_in,
                              void* d_out, int out_size, void* d_ws, size_t ws_size,
                              hipStream_t stream) {
  const float* x = (const float*)d_in[0];
  const int* ei = (const int*)d_in[1];
  const float* W1 = (const float*)d_in[2];
  const float* b1 = (const float*)d_in[3];
  const float* W2 = (const float*)d_in[4];
  const float* b2 = (const float*)d_in[5];
  float* out = (float*)d_out;

  const int n = in_sizes[0] / IN_F;   // 50000
  const int e = in_sizes[1] / 2;      // 800000
  const int* e_src = ei;
  const int* e_dst = ei + e;

  uint8_t* ws = (uint8_t*)d_ws;
  size_t off = 0;
  auto carve = [&](size_t bytes) {
    uint8_t* p = ws + off;
    off = (off + bytes + 255) & ~(size_t)255;
    return p;
  };
  short* h1 = (short*)carve((size_t)n * HID * 2);
  short* h2 = (short*)carve((size_t)n * HID * 2);
  short* t2 = (short*)carve((size_t)n * OUTF * 2);
  short* w1t = (short*)carve((size_t)HID * IN_F * 2);
  short* w2t = (short*)carve((size_t)OUTF * HID * 2);
  int* cnt = (int*)carve((size_t)(n + 1) * 4);  // cnt[n] = global alloc counter
  int* rowp = (int*)carve((size_t)(n + 1) * 4);
  int* cursor = (int*)carve((size_t)n * 4);
  float* dinv = (float*)carve((size_t)n * 4);
  int* ssrc = (int*)carve((size_t)e * 4);
  (void)n_in; (void)out_size; (void)ws_size;

  // prep: both weight transposes + zero cnt[n+1] in one launch
  {
    int total = IN_F * HID + HID * OUTF + (n + 1);
    k_prep<<<(total + 255) / 256, 256, 0, stream>>>(W1, w1t, W2, w2t, cnt, n + 1);
  }

  // CSR build: hist -> scan-free alloc -> fill (3 launches, was 5)
  k_hist<<<(e + 255) / 256, 256, 0, stream>>>(e_dst, cnt, e);
  k_alloc<<<(n + 255) / 256, 256, 0, stream>>>(cnt, rowp, cursor, dinv, &cnt[n], n);
  k_fill<<<(e + 255) / 256, 256, 0, stream>>>(e_src, e_dst, cursor, ssrc, e);

  // layer 1
  k_gemm1<<<(n + 127) / 128, 256, 0, stream>>>(x, w1t, h1, n, IN_F);
  k_agg3<HID, true, short><<<(n + 3) / 4, 256, 0, stream>>>(h1, rowp, cnt, ssrc, dinv, b1, h2, n);

  // layer 2
  {
    dim3 grid((n + 127) / 128, OUTF / 128);
    k_gemm_a<<<grid, 256, 0, stream>>>(h2, w2t, t2, n, OUTF, HID);
  }
  k_agg3<OUTF, false, float><<<(n + 3) / 4, 256, 0, stream>>>(t2, rowp, cnt, ssrc, dinv, b2, out, n);
}